// Round 2
// baseline (1241.876 us; speedup 1.0000x reference)
//
#include <hip/hip_runtime.h>
#include <math.h>

// InfoNCE loss, one THREAD per row (D=512). Zero shuffles in the hot loop;
// register double-buffered 64B-per-array chunks so each 64B line is fully
// consumed by its owning thread (HBM traffic stays 1x, L1 absorbs divergence).

#define D_DIM 512
#define F4_PER_ROW 128          // 512 floats = 128 float4
#define CHUNK 4                 // float4 per chunk per array = 64 B = 1 cache line
#define NCHUNK (F4_PER_ROW / CHUNK)   // 32
#define TEMP_INV (1.0f / 1.5f)
#define EPS_N 1e-12f

constexpr int TPB = 256;
constexpr int WAVES_PER_BLOCK = TPB / 64;

__global__ __launch_bounds__(TPB) void infonce_rows(
    const float* __restrict__ a, const float* __restrict__ p,
    const float* __restrict__ n, float* __restrict__ partial, int B) {
  const int row = blockIdx.x * TPB + threadIdx.x;

  float loss = 0.0f;
  if (row < B) {
    const float4* __restrict__ a4 = (const float4*)a + (size_t)row * F4_PER_ROW;
    const float4* __restrict__ p4 = (const float4*)p + (size_t)row * F4_PER_ROW;
    const float4* __restrict__ n4 = (const float4*)n + (size_t)row * F4_PER_ROW;

    float aa = 0.f, pp = 0.f, nn = 0.f, ap = 0.f, an = 0.f;

    float4 ab[2][CHUNK], pb[2][CHUNK], nb[2][CHUNK];
#pragma unroll
    for (int k = 0; k < CHUNK; ++k) {
      ab[0][k] = a4[k];
      pb[0][k] = p4[k];
      nb[0][k] = n4[k];
    }

#pragma unroll
    for (int c = 0; c < NCHUNK; ++c) {
      const int cur = c & 1;
      const int nxt = cur ^ 1;
      if (c + 1 < NCHUNK) {
        const int base = (c + 1) * CHUNK;
#pragma unroll
        for (int k = 0; k < CHUNK; ++k) {
          ab[nxt][k] = a4[base + k];
          pb[nxt][k] = p4[base + k];
          nb[nxt][k] = n4[base + k];
        }
      }
#pragma unroll
      for (int k = 0; k < CHUNK; ++k) {
        const float4 av = ab[cur][k];
        const float4 pv = pb[cur][k];
        const float4 nv = nb[cur][k];
        aa = fmaf(av.x, av.x, fmaf(av.y, av.y, fmaf(av.z, av.z, fmaf(av.w, av.w, aa))));
        pp = fmaf(pv.x, pv.x, fmaf(pv.y, pv.y, fmaf(pv.z, pv.z, fmaf(pv.w, pv.w, pp))));
        nn = fmaf(nv.x, nv.x, fmaf(nv.y, nv.y, fmaf(nv.z, nv.z, fmaf(nv.w, nv.w, nn))));
        ap = fmaf(av.x, pv.x, fmaf(av.y, pv.y, fmaf(av.z, pv.z, fmaf(av.w, pv.w, ap))));
        an = fmaf(av.x, nv.x, fmaf(av.y, nv.y, fmaf(av.z, nv.z, fmaf(av.w, nv.w, an))));
      }
    }

    const float na = fmaxf(sqrtf(aa), EPS_N);
    const float np_ = fmaxf(sqrtf(pp), EPS_N);
    const float nv_ = fmaxf(sqrtf(nn), EPS_N);
    const float pos = ap / (na * np_);
    const float neg = an / (na * nv_);
    const float l0 = pos * TEMP_INV;
    const float l1 = neg * TEMP_INV;
    const float m = fmaxf(l0, l1);
    loss = (m + logf(expf(l0 - m) + expf(l1 - m))) - l0;
  }

  // Block-level reduction of per-thread losses (once per thread; negligible).
#pragma unroll
  for (int off = 32; off > 0; off >>= 1) loss += __shfl_xor(loss, off);

  __shared__ float sh[WAVES_PER_BLOCK];
  const int lane = threadIdx.x & 63;
  const int wv = threadIdx.x >> 6;
  if (lane == 0) sh[wv] = loss;
  __syncthreads();
  if (threadIdx.x == 0) {
    float s = 0.f;
#pragma unroll
    for (int i = 0; i < WAVES_PER_BLOCK; ++i) s += sh[i];
    partial[blockIdx.x] = s;
  }
}

__global__ __launch_bounds__(256) void reduce_partials(
    const float* __restrict__ partial, float* __restrict__ out,
    int nparts, int B) {
  __shared__ float sh[256];
  float s = 0.f;
  for (int i = threadIdx.x; i < nparts; i += 256) s += partial[i];
  sh[threadIdx.x] = s;
  __syncthreads();
  for (int off = 128; off > 0; off >>= 1) {
    if (threadIdx.x < off) sh[threadIdx.x] += sh[threadIdx.x + off];
    __syncthreads();
  }
  if (threadIdx.x == 0) out[0] = sh[0] / (float)B;
}

extern "C" void kernel_launch(void* const* d_in, const int* in_sizes, int n_in,
                              void* d_out, int out_size, void* d_ws, size_t ws_size,
                              hipStream_t stream) {
  const float* a = (const float*)d_in[0];   // anchors
  const float* p = (const float*)d_in[1];   // positives
  const float* n = (const float*)d_in[2];   // negatives
  float* partial = (float*)d_ws;
  float* out = (float*)d_out;
  const int B = in_sizes[0] / D_DIM;
  const int nblocks = (B + TPB - 1) / TPB;  // 512 for B=131072

  infonce_rows<<<nblocks, TPB, 0, stream>>>(a, p, n, partial, B);
  reduce_partials<<<1, 256, 0, stream>>>(partial, out, nblocks, B);
}